// Round 9
// baseline (305.583 us; speedup 1.0000x reference)
//
#include <hip/hip_runtime.h>
#include <hip/hip_bf16.h>

typedef __bf16 bf16x8 __attribute__((ext_vector_type(8)));
typedef __bf16 bf16x4 __attribute__((ext_vector_type(4)));
typedef short  s16x4  __attribute__((ext_vector_type(4)));
typedef float  f32x4  __attribute__((ext_vector_type(4)));

#define B_ 256
#define N_ 256
#define D_ 128
#define PSRC 136                                  // row-major LDS pitch (bf16 elems)
#define OFF_SRCT (N_ * PSRC * 2)                  // 69632
#define LDS_BYTES (OFF_SRCT + D_ * 512)           // 135168

// 16x16x16 bf16 MFMA. A: m=lane&15, k=(lane>>4)*4+e. B: n=lane&15, same k.
// C/D: col n=lane&15, row m=(lane>>4)*4+reg.
__device__ __forceinline__ f32x4 mfma16(bf16x4 a, bf16x4 b, f32x4 c) {
    union { bf16x4 h; s16x4 s; } ua, ub;
    ua.h = a; ub.h = b;
    return __builtin_amdgcn_mfma_f32_16x16x16bf16_1k(ua.s, ub.s, c, 0, 0, 0);
}

// Arch-VGPR budget is hard-pinned at 128 for this kernel (observed across all
// launch_bounds variants). The kernel is structured so peak ARCH live set
// fits 128: variants split into two j-passes (asf 32 regs, not 64), adj held
// packed 4x8b (16 regs, not 64), partial-p linearity merges the passes.
__global__ __launch_bounds__(512, 1) void gat_fused(
    const float* __restrict__ src, const int* __restrict__ adj,
    const float* __restrict__ a0, const float* __restrict__ a1,
    const float* __restrict__ a2, const float* __restrict__ a3,
    const float* __restrict__ bias, float* __restrict__ out)
{
    extern __shared__ char lds[];
    __bf16* s_src  = (__bf16*)lds;                // [256][136] bf16 row-major
    char*   s_srcT = lds + OFF_SRCT;              // [128][256] bf16, XOR-swizzled rows
    const int t    = threadIdx.x;
    const int lane = t & 63;
    const int wave = t >> 6;
    const int g    = lane >> 4;                   // 0..3
    const int r16  = lane & 15;                   // 0..15

    const int b = blockIdx.x;
    const float* __restrict__ srcb = src + (size_t)b * (N_ * D_);
    const int*   __restrict__ adjb = adj + (size_t)b * (N_ * N_);
    float*       __restrict__ outb = out + (size_t)b * (N_ * D_);

    unsigned adjp[16];                            // packed adj: 4 x 8-bit per u32
    // ---- adj for half 0 (this wave's rows), loaded before staging ----
    {
        const int4* __restrict__ ap = (const int4*)(adjb + (wave * 16 + r16) * N_ + g * 4);
        int4 tmp[16];
        #pragma unroll
        for (int jt = 0; jt < 16; ++jt) tmp[jt] = ap[jt * 4];
        #pragma unroll
        for (int jt = 0; jt < 16; ++jt)
            adjp[jt] = (unsigned)tmp[jt].x | ((unsigned)tmp[jt].y << 8) |
                       ((unsigned)tmp[jt].z << 16) | ((unsigned)tmp[jt].w << 24);
    }

    // ---------------- stage src[b]: row-major bf16 + swizzled transpose ----------------
    {
        const int d   = t & 127;
        const int jb  = (t >> 7) * 64;
        const int swz = (d & 7) << 4;
        #pragma unroll
        for (int jo = 0; jo < 64; jo += 16) {
            float v[16];
            #pragma unroll
            for (int q = 0; q < 16; ++q) v[q] = srcb[(jb + jo + q) * D_ + d];
            #pragma unroll
            for (int q = 0; q < 16; ++q) s_src[(jb + jo + q) * PSRC + d] = (__bf16)v[q];
            #pragma unroll
            for (int q = 0; q < 16; q += 4) {
                bf16x4 w;
                w[0] = (__bf16)v[q];     w[1] = (__bf16)v[q + 1];
                w[2] = (__bf16)v[q + 2]; w[3] = (__bf16)v[q + 3];
                *(bf16x4*)(s_srcT + (d * 512 + ((2 * (jb + jo + q)) ^ swz))) = w;
            }
        }
    }
    __syncthreads();

    const int swzT = (r16 & 7) << 4;

    #pragma unroll 1
    for (int half = 0; half < 2; ++half) {
        const int i0 = half * 128 + wave * 16;    // this wave's 16 output rows

        float s = 0.f;
        f32x4 oacc[8];
        #pragma unroll
        for (int dt = 0; dt < 8; ++dt) oacc[dt] = (f32x4){0, 0, 0, 0};

        bf16x8 sfA[4], sfB[4];                    // two variants' scaled fragments

        // helper: build sfA/sfB = bf16(src[i0+r16,:] * a{A,B}) for one variant pair
        auto make2 = [&](const float* __restrict__ aA, const float* __restrict__ aB) {
            #pragma unroll
            for (int kc = 0; kc < 4; ++kc) {
                const bf16x8 base =
                    *(const bf16x8*)&s_src[(i0 + r16) * PSRC + kc * 32 + g * 8];
                float bf[8];
                #pragma unroll
                for (int e = 0; e < 8; ++e) bf[e] = (float)base[e];
                const float4 aA0 = *(const float4*)(aA + kc * 32 + g * 8);
                const float4 aA1 = *(const float4*)(aA + kc * 32 + g * 8 + 4);
                const float4 aB0 = *(const float4*)(aB + kc * 32 + g * 8);
                const float4 aB1 = *(const float4*)(aB + kc * 32 + g * 8 + 4);
                bf16x8 fA, fB;
                fA[0] = (__bf16)(bf[0] * aA0.x); fA[1] = (__bf16)(bf[1] * aA0.y);
                fA[2] = (__bf16)(bf[2] * aA0.z); fA[3] = (__bf16)(bf[3] * aA0.w);
                fA[4] = (__bf16)(bf[4] * aA1.x); fA[5] = (__bf16)(bf[5] * aA1.y);
                fA[6] = (__bf16)(bf[6] * aA1.z); fA[7] = (__bf16)(bf[7] * aA1.w);
                fB[0] = (__bf16)(bf[0] * aB0.x); fB[1] = (__bf16)(bf[1] * aB0.y);
                fB[2] = (__bf16)(bf[2] * aB0.z); fB[3] = (__bf16)(bf[3] * aB0.w);
                fB[4] = (__bf16)(bf[4] * aB1.x); fB[5] = (__bf16)(bf[5] * aB1.y);
                fB[6] = (__bf16)(bf[6] * aB1.z); fB[7] = (__bf16)(bf[7] * aB1.w);
                sfA[kc] = fA; sfB[kc] = fB;
            }
        };

        // helper: one pass over all j-tiles for variant pair (vA, vB).
        // Adds partial exp to s and partial PV to oacc (linearity of both).
        auto pass = [&](int vA, int vB) {
            #pragma unroll
            for (int jt = 0; jt < 16; ++jt) {
                bf16x8 bfr[4];
                #pragma unroll
                for (int kc = 0; kc < 4; ++kc)
                    bfr[kc] = *(const bf16x8*)
                        &s_src[(jt * 16 + r16) * PSRC + kc * 32 + g * 8];
                f32x4 acc0 = {0,0,0,0}, acc1 = {0,0,0,0};
                #pragma unroll
                for (int kc = 0; kc < 4; ++kc) {
                    acc0 = __builtin_amdgcn_mfma_f32_16x16x32_bf16(bfr[kc], sfA[kc], acc0, 0, 0, 0);
                    acc1 = __builtin_amdgcn_mfma_f32_16x16x32_bf16(bfr[kc], sfB[kc], acc1, 0, 0, 0);
                }
                const unsigned pk = adjp[jt];
                bf16x4 pf;
                #pragma unroll
                for (int r = 0; r < 4; ++r) {
                    const int a = (pk >> (8 * r)) & 0xff;
                    float v = (a == vA) ? acc0[r]
                            : ((a == vB) ? acc1[r] : -3.402823466e38f);
                    v = fmaxf(v, 0.2f * v);        // leaky_relu
                    const float e = __builtin_exp2f(v * 1.4426950408889634f);
                    s += e;                        // masked/other-pass -> exp2(-inf)=0
                    pf[r] = (__bf16)e;
                }
                const int jb2 = 32 * jt + 8 * g;
                #pragma unroll
                for (int dt = 0; dt < 8; ++dt) {
                    const int d = dt * 16 + r16;
                    const bf16x4 vf = *(const bf16x4*)(s_srcT + (d * 512 + (jb2 ^ swzT)));
                    oacc[dt] = mfma16(pf, vf, oacc[dt]);
                }
            }
        };

        make2(a0, a1);
        pass(1, 2);
        make2(a2, a3);
        pass(3, 4);

        // ---- row-sum reduce across the 4 g-groups sharing P-domain row i0 + r16 ----
        s += __shfl_xor(s, 16);
        s += __shfl_xor(s, 32);
        const float sc = 1.0f / s;                 // normalizer for row i0 + r16

        // PV transposed the lane->row mapping: oacc rows are i0 + g*4 + r.
        float scv[4];
        #pragma unroll
        for (int r = 0; r < 4; ++r) scv[r] = __shfl(sc, g * 4 + r);

        // ---- adj for half 1: load+pack now (overlaps epilogue; asf regs dead) ----
        if (half == 0) {
            const int4* __restrict__ ap =
                (const int4*)(adjb + (128 + wave * 16 + r16) * N_ + g * 4);
            int4 tmp[16];
            #pragma unroll
            for (int jt = 0; jt < 16; ++jt) tmp[jt] = ap[jt * 4];
            #pragma unroll
            for (int jt = 0; jt < 16; ++jt)
                adjp[jt] = (unsigned)tmp[jt].x | ((unsigned)tmp[jt].y << 8) |
                           ((unsigned)tmp[jt].z << 16) | ((unsigned)tmp[jt].w << 24);
        }

        // ---- epilogue: normalize (per OUTPUT row) + bias, coalesced f32 stores ----
        #pragma unroll
        for (int dt = 0; dt < 8; ++dt) {
            const float bvv = bias[dt * 16 + r16];
            #pragma unroll
            for (int r = 0; r < 4; ++r) {
                outb[(i0 + g * 4 + r) * D_ + dt * 16 + r16] = oacc[dt][r] * scv[r] + bvv;
            }
        }
    }
}

extern "C" void kernel_launch(void* const* d_in, const int* in_sizes, int n_in,
                              void* d_out, int out_size, void* d_ws, size_t ws_size,
                              hipStream_t stream) {
    const float* src  = (const float*)d_in[0];
    const int*   adj  = (const int*)d_in[1];
    const float* a0   = (const float*)d_in[2];
    const float* a1   = (const float*)d_in[3];
    const float* a2   = (const float*)d_in[4];
    const float* a3   = (const float*)d_in[5];
    const float* bias = (const float*)d_in[6];
    float* out = (float*)d_out;

    (void)hipFuncSetAttribute((const void*)gat_fused,
                              hipFuncAttributeMaxDynamicSharedMemorySize, LDS_BYTES);
    gat_fused<<<B_, 512, LDS_BYTES, stream>>>(src, adj, a0, a1, a2, a3, bias, out);
}